// Round 1
// baseline (502.397 us; speedup 1.0000x reference)
//
#include <hip/hip_runtime.h>
#include <math.h>

// Sinkhorn W2 loss: 16 independent (b0,b1) pairs, 128x128 images.
// One block per pair; whole 10-iteration loop + final blur + loss fused
// into a single kernel launch. Log-domain blur computed as
//   M + log( G conv G conv exp(x - M) )   (inter-axis log/exp cancels).
#define NN   128
#define NPAD 129          // LDS row stride (odd -> bank-conflict-free both passes)
#define RW   22           // Gaussian window radius: tap at |d|=22 is ~1.5e-13
#define NH   21           // halfsteps: 20 sinkhorn (10 iters x 2) + 1 final blur
#define NT   1024

struct GTab { float g[RW + 1]; };

__global__ __launch_bounds__(NT, 1)
void sinkhorn_w2(const float* __restrict__ a0, const float* __restrict__ a1,
                 float* __restrict__ out, GTab gt)
{
    extern __shared__ float lds[];
    float* X   = lds;                    // 128*129 floats
    float* Y   = lds + NN * NPAD;        // 128*129 floats
    float* red = lds + 2 * NN * NPAD;    // 64 floats reduction scratch

    const int t    = threadIdx.x;
    const int pair = blockIdx.x;                     // = b0*4 + b1
    const float* A0 = a0 + (pair >> 2) * (NN * NN);  // a0[b0]
    const float* A1 = a1 + (pair & 3)  * (NN * NN);  // a1[b1]

    const int lane = t & 63;
    const int wid  = t >> 6;

    // phi1 = 0 initially (initial phi0 is never read by the recurrence)
    for (int i = t; i < NN * NPAD; i += NT) X[i] = 0.0f;

    float sav[16];        // final phi0, kept in registers
    float dot1  = 0.0f;   // sum phi1*a1 partial
    float Mlast = 0.0f;   // max used in the final blur

    float* S = X;         // current source (log-domain phi)
    float* D = Y;         // scratch / dest

    __syncthreads();

    #pragma unroll 1
    for (int h = 0; h < NH; ++h) {
        const bool isFinal = (h == NH - 1);      // final extra blur of phi1
        const bool doSave  = (h == NH - 2);      // h==19: source is final phi0
        const float* Acur  = (h & 1) ? A1 : A0;  // la for the fused finalize

        // ---- 1. M = max over S (valid 128x128 region) ----
        float m = -3.4e38f;
        #pragma unroll
        for (int k = 0; k < 16; ++k) {
            int idx  = t + NT * k;
            int addr = (idx >> 7) * NPAD + (idx & 127);
            m = fmaxf(m, S[addr]);
        }
        #pragma unroll
        for (int off = 1; off < 64; off <<= 1)
            m = fmaxf(m, __shfl_xor(m, off, 64));
        if (lane == 0) red[wid] = m;
        __syncthreads();
        if (wid == 0) {
            float x = (lane < 16) ? red[lane] : -3.4e38f;
            #pragma unroll
            for (int off = 1; off < 16; off <<= 1)
                x = fmaxf(x, __shfl_xor(x, off, 64));
            if (lane == 0) red[0] = x;
        }
        __syncthreads();
        const float M = red[0];
        __syncthreads();
        if (isFinal) Mlast = M;

        // ---- 2. exp in place (+ save phi0 / accumulate phi1*a1) ----
        #pragma unroll
        for (int k = 0; k < 16; ++k) {
            int idx  = t + NT * k;
            int addr = (idx >> 7) * NPAD + (idx & 127);
            float v = S[addr];
            if (doSave)  sav[k] = v;
            if (isFinal) dot1 += v * A1[idx];
            S[addr] = __expf(v - M);
        }
        __syncthreads();

        // ---- 3. row conv S -> D (lanes = consecutive rows; stride 129 -> free)
        {
            const int r  = t & 127;
            const int ob = (t >> 7) << 4;     // wave-uniform output base
            float acc[16];
            #pragma unroll
            for (int j = 0; j < 16; ++j) acc[j] = 0.0f;
            #pragma unroll
            for (int q = -RW; q <= 15 + RW; ++q) {
                int x  = ob + q;
                int xc = x < 0 ? 0 : (x > NN - 1 ? NN - 1 : x);
                float v = S[r * NPAD + xc];
                v = (x >= 0 && x < NN) ? v : 0.0f;
                #pragma unroll
                for (int j = 0; j < 16; ++j) {
                    int d = q - j; int ad = d < 0 ? -d : d;
                    if (ad <= RW) acc[j] = fmaf(v, gt.g[ad], acc[j]);
                }
            }
            #pragma unroll
            for (int j = 0; j < 16; ++j) D[r * NPAD + ob + j] = acc[j];
        }
        __syncthreads();

        // ---- 4. col conv IN PLACE on D, fused finalize ----
        {
            const int c  = t & 127;
            const int rb = (t >> 7) << 4;
            float acc[16];
            #pragma unroll
            for (int j = 0; j < 16; ++j) acc[j] = 0.0f;
            #pragma unroll
            for (int q = -RW; q <= 15 + RW; ++q) {
                int y  = rb + q;
                int yc = y < 0 ? 0 : (y > NN - 1 ? NN - 1 : y);
                float v = D[yc * NPAD + c];
                v = (y >= 0 && y < NN) ? v : 0.0f;
                #pragma unroll
                for (int j = 0; j < 16; ++j) {
                    int d = q - j; int ad = d < 0 ? -d : d;
                    if (ad <= RW) acc[j] = fmaf(v, gt.g[ad], acc[j]);
                }
            }
            __syncthreads();   // all reads of D done before in-place writes
            if (isFinal) {
                #pragma unroll
                for (int j = 0; j < 16; ++j)
                    D[(rb + j) * NPAD + c] = acc[j];   // keep linear conv
            } else {
                #pragma unroll
                for (int j = 0; j < 16; ++j) {
                    float la = __logf(fmaxf(Acur[(rb + j) * NN + c], 1e-20f));
                    D[(rb + j) * NPAD + c] = la - M - __logf(acc[j]);
                }
            }
        }
        __syncthreads();

        float* tmp = S; S = D; D = tmp;   // result now in S
    }

    // ---- final pointwise + loss reduction ----
    // p = exp(phi0 + blurlog) = conv * exp(phi0 + Mlast)
    float part = dot1;
    #pragma unroll
    for (int k = 0; k < 16; ++k) {
        int idx  = t + NT * k;
        int addr = (idx >> 7) * NPAD + (idx & 127);
        float conv = S[addr];
        float p    = conv * __expf(sav[k] + Mlast);
        part += sav[k] * A0[idx] - p;
    }
    #pragma unroll
    for (int off = 1; off < 64; off <<= 1)
        part += __shfl_xor(part, off, 64);
    if (lane == 0) red[wid] = part;
    __syncthreads();
    if (t == 0) {
        float s = 0.0f;
        #pragma unroll
        for (int w = 0; w < 16; ++w) s += red[w];
        out[pair] = 1e-3f * s;
    }
}

extern "C" void kernel_launch(void* const* d_in, const int* in_sizes, int n_in,
                              void* d_out, int out_size, void* d_ws, size_t ws_size,
                              hipStream_t stream) {
    const float* a0 = (const float*)d_in[0];   // (4,128,128) f32
    const float* a1 = (const float*)d_in[1];   // (4,128,128) f32
    float* out = (float*)d_out;                // (4,4) f32

    // Gaussian taps computed on host exactly as the reference's f32 constants:
    // b = f32(1e-3) * 16384 = 16.384000778198242
    GTab gt;
    const float bb = 1e-3f / ((1.0f / 128.0f) * (1.0f / 128.0f));
    for (int d = 0; d <= RW; ++d)
        gt.g[d] = expf(-(float)(d * d) / bb);

    const size_t ldsBytes = (size_t)(2 * NN * NPAD + 64) * sizeof(float);
    // opt in to >64KB dynamic LDS (idempotent; host-side, capture-safe)
    (void)hipFuncSetAttribute(reinterpret_cast<const void*>(sinkhorn_w2),
                              hipFuncAttributeMaxDynamicSharedMemorySize,
                              (int)ldsBytes);

    hipLaunchKernelGGL(sinkhorn_w2, dim3(16), dim3(NT), ldsBytes, stream,
                       a0, a1, out, gt);
}

// Round 2
// 309.645 us; speedup vs baseline: 1.6225x; 1.6225x over previous
//
#include <hip/hip_runtime.h>
#include <math.h>

// Sinkhorn W2, 16 pairs of 128x128 images, one block per pair.
// Linear-domain iteration: S = exp(phi - B) (per-pair scalar B), per halfstep
//   T = conv_row(conv_col(r*S)),  S' = max(a,1e-20)/T,  r' = 1/max(S'),
//   B' = -log(max(S')) - B
// (log/exp of the reference's log-domain blur cancels analytically).
// Log-domain quantities recovered only at the end.
#define NN 128
#define ST 148          // LDS row stride in dwords: 128 data + 20 zero pad
#define SB 20           // 20-dword zero guard before S
#define RW 17           // g[17]=2.2e-8: below f32 summation precision
#define NT 1024
#define NH 21           // 20 sinkhorn halfsteps + 1 final blur

struct GTab { float g[RW + 1]; };

// 1-D 35-tap conv: 16 outputs [ob,ob+16) of one padded row, inputs read as
// float4 from window [ob-20, ob+36). base4 = dword_base/4 (16B aligned).
__device__ __forceinline__ void conv_line(const float4* __restrict__ L4, int base4,
                                          const GTab& gt, float (&acc)[16])
{
    #pragma unroll
    for (int j = 0; j < 16; ++j) acc[j] = 0.0f;
    #pragma unroll
    for (int k4 = 0; k4 < 14; ++k4) {
        float4 v = L4[base4 + k4];
        #pragma unroll
        for (int e = 0; e < 4; ++e) {
            float vv = (e == 0) ? v.x : (e == 1) ? v.y : (e == 2) ? v.z : v.w;
            const int xr = 4 * k4 + e - 20;          // position relative to ob
            #pragma unroll
            for (int j = 0; j < 16; ++j) {
                const int d = xr - j;
                if (d >= -RW && d <= RW) {
                    const int ad = d < 0 ? -d : d;
                    acc[j] = fmaf(vv, gt.g[ad], acc[j]);
                }
            }
        }
    }
}

__global__ __launch_bounds__(NT, 1)
void sinkhorn_w2(const float* __restrict__ a0, const float* __restrict__ a1,
                 float* __restrict__ out, GTab gt)
{
    extern __shared__ float lds[];
    constexpr int DB = SB + NN * ST + 20;   // 18984 (D has its own 20-dword guard)
    constexpr int RB = DB + NN * ST;        // 37928: reduction scratch
    float* red = lds + RB;
    const float4* L4 = (const float4*)lds;

    const int t = threadIdx.x;
    const int pair = blockIdx.x;
    const float* __restrict__ A0 = a0 + (pair >> 2) * (NN * NN);
    const float* __restrict__ A1 = a1 + (pair & 3) * (NN * NN);
    const int lane = t & 63, wid = t >> 6;
    const int u = t & 127;        // row index (phase1) / column index (phase2)
    const int s = t >> 7;         // 0..7
    const int ob = s << 4;        // output base within the line

    // zero everything (guards + pads stay zero forever), then S data = 1 (phi=0)
    for (int i = t; i < RB + 32; i += NT) lds[i] = 0.0f;
    __syncthreads();
    #pragma unroll
    for (int k = 0; k < 16; ++k) {
        int idx = t + NT * k;
        lds[SB + (idx >> 7) * ST + (idx & 127)] = 1.0f;
    }

    // this thread's fixed 16 elements: (row ob+j, col u) — matches phase-2 writes
    float Ap0[16], Ap1[16], sav[16];
    float SA0 = 0.f, SA1 = 0.f, D0 = 0.f, D1 = 0.f, Pp = 0.f;
    #pragma unroll
    for (int j = 0; j < 16; ++j) {
        Ap0[j] = A0[(ob + j) * NN + u];
        Ap1[j] = A1[(ob + j) * NN + u];
        SA0 += Ap0[j]; SA1 += Ap1[j];
        sav[j] = 0.f;
    }
    float B = 0.f, r = 1.f, B18 = 0.f, B19 = 0.f, lr20 = 0.f;
    __syncthreads();

    #pragma unroll 1
    for (int k = 0; k < NH; ++k) {
        if (k == 18) B18 = B;     // bias of the S written this halfstep (= final phi0)
        if (k == 19) B19 = B;     // = final phi1

        // ---- phase 1: row conv of r*S -> D (transposed write, lane-stride-1) ----
        {
            float acc[16];
            conv_line(L4, 37 * u + 4 * s, gt, acc);   // (SB + u*ST + ob - 20)/4
            const int wb = DB + ob * ST + u;
            #pragma unroll
            for (int j = 0; j < 16; ++j) lds[wb + j * ST] = acc[j] * r;
        }
        __syncthreads();

        // ---- phase 2: col conv D -> T, finalize S' = max(a,floor)/T ----
        float vmax = 0.f;
        {
            float acc[16];
            conv_line(L4, 4741 + 37 * u + 4 * s, gt, acc);  // (DB + u*ST + ob - 20)/4
            const int wb = SB + ob * ST + u;
            if (k < NH - 1) {
                if ((k & 1) == 0) {                       // producing phi0 (uses a0)
                    #pragma unroll
                    for (int j = 0; j < 16; ++j) {
                        float amx = fmaxf(Ap0[j], 1e-20f);
                        float Un  = amx * __builtin_amdgcn_rcpf(acc[j]);
                        if (k == 18) {
                            sav[j] = Un;                              // S18 for the p-term
                            D0 = fmaf(Ap0[j], __logf(Un), D0);        // sum a0*log(S18)
                        }
                        vmax = fmaxf(vmax, Un);
                        lds[wb + j * ST] = Un;
                    }
                } else {                                   // producing phi1 (uses a1)
                    #pragma unroll
                    for (int j = 0; j < 16; ++j) {
                        float amx = fmaxf(Ap1[j], 1e-20f);
                        float Un  = amx * __builtin_amdgcn_rcpf(acc[j]);
                        if (k == 19) D1 = fmaf(Ap1[j], __logf(Un), D1);  // sum a1*log(S19)
                        vmax = fmaxf(vmax, Un);
                        lds[wb + j * ST] = Un;
                    }
                }
            } else {
                // final blur: acc = T20; p-term partial = sum S18*T20
                #pragma unroll
                for (int j = 0; j < 16; ++j) Pp = fmaf(sav[j], acc[j], Pp);
            }
        }

        // ---- per-pair max reduce -> r, B update (scalar bookkeeping) ----
        if (k < NH - 1) {
            #pragma unroll
            for (int off = 1; off < 64; off <<= 1)
                vmax = fmaxf(vmax, __shfl_xor(vmax, off, 64));
            if (lane == 0) red[wid] = vmax;
        }
        __syncthreads();                     // also orders phase-2 S writes
        if (k < NH - 1) {
            if (wid == 0) {
                float x = (lane < 16) ? red[lane] : 0.f;
                #pragma unroll
                for (int off = 1; off < 16; off <<= 1)
                    x = fmaxf(x, __shfl_xor(x, off, 64));
                if (lane == 0) red[16] = x;
            }
            __syncthreads();
            float mstar = red[16];
            if (k == 19) lr20 = -__logf(mstar);          // log r20 for the p-term scale
            B = -__logf(mstar) - B;
            r = __builtin_amdgcn_rcpf(mstar);
        }
    }

    // loss = eps*( sum phi0*a0 + sum phi1*a1 - sum p )
    //      = eps*( D0 + B18*SA0 + D1 + B19*SA1 - exp(B18+B19-lr20)*sum(S18*T20) )
    float part = D0 + D1 + B18 * SA0 + B19 * SA1
               - expf(B18 + B19 - lr20) * Pp;
    #pragma unroll
    for (int off = 1; off < 64; off <<= 1)
        part += __shfl_xor(part, off, 64);
    __syncthreads();
    if (lane == 0) red[wid] = part;
    __syncthreads();
    if (t == 0) {
        float ssum = 0.f;
        #pragma unroll
        for (int w = 0; w < 16; ++w) ssum += red[w];
        out[pair] = 1e-3f * ssum;
    }
}

extern "C" void kernel_launch(void* const* d_in, const int* in_sizes, int n_in,
                              void* d_out, int out_size, void* d_ws, size_t ws_size,
                              hipStream_t stream) {
    const float* a0 = (const float*)d_in[0];   // (4,128,128) f32
    const float* a1 = (const float*)d_in[1];   // (4,128,128) f32
    float* out = (float*)d_out;                // (4,4) f32

    GTab gt;
    const float bb = 1e-3f / ((1.0f / 128.0f) * (1.0f / 128.0f));  // 16.384
    for (int d = 0; d <= RW; ++d)
        gt.g[d] = expf(-(float)(d * d) / bb);

    const size_t ldsBytes = (size_t)(37928 + 32) * sizeof(float);  // 151,840 B
    (void)hipFuncSetAttribute(reinterpret_cast<const void*>(sinkhorn_w2),
                              hipFuncAttributeMaxDynamicSharedMemorySize,
                              (int)ldsBytes);

    hipLaunchKernelGGL(sinkhorn_w2, dim3(16), dim3(NT), ldsBytes, stream,
                       a0, a1, out, gt);
}

// Round 3
// 238.618 us; speedup vs baseline: 2.1054x; 1.2977x over previous
//
#include <hip/hip_runtime.h>
#include <math.h>

// Sinkhorn W2, 16 pairs of 128x128 images, one block per pair, fully fused.
// Linear-domain iteration (log/exp of the reference's log-domain blur cancels):
//   T = conv_col(conv_row(r*S)),  S' = max(a,1e-20)/T,  r' = 1/max(S'),
//   B' = -log(max(S')) - B
// Final-blur p-term collapses analytically: sum p == sum max(a1,1e-20)
// (Gaussian operator symmetry + the phi1 update identity), so only 20
// halfsteps are needed and no final blur.
//
// LDS: row stride 149 dwords (odd mod 32 -> all access patterns cover the
// 32 banks evenly; b32/read2 only, no b128 alignment constraint).
#define NN 128
#define ST 149                      // row stride in dwords (21-dword tail pad)
#define RW 16                       // g[16]=1.6e-7: below f32 noise floor
#define NH 20                       // 10 iterations x 2 halfsteps
#define NT 1024
#define SBASE 16                    // 16-dword zero guard before S rows
#define DBASE (SBASE + NN*ST + 16)  // 19104 (16-dword guard before D rows)
#define REDB  (DBASE + NN*ST)       // 38176 (D row-127 tail pad ends < here)
#define TOTD  (REDB + 16)           // 38192 dwords = 152,768 B

struct GTab { float g[RW + 1]; };

__global__ __launch_bounds__(NT, 4)
void sinkhorn_w2(const float* __restrict__ a0, const float* __restrict__ a1,
                 float* __restrict__ out, GTab gt)
{
    extern __shared__ float lds[];
    float* red = lds + REDB;

    const int t = threadIdx.x;
    const int pair = blockIdx.x;
    const float* __restrict__ A0 = a0 + (pair >> 2) * (NN * NN);
    const float* __restrict__ A1 = a1 + (pair & 3) * (NN * NN);
    const int lane = t & 63, wid = t >> 6;
    const int u  = t & 127;          // row index (phase1) / col index (phase2)
    const int ob = (t >> 7) << 4;    // 16-output base within the line

    // zero all of LDS (guards + pads stay zero forever)
    for (int i = t; i < TOTD; i += NT) lds[i] = 0.0f;
    __syncthreads();
    // S = 1  (phi1 = 0 initially; initial phi0 never read)
    #pragma unroll
    for (int kk = 0; kk < 16; ++kk) {
        int idx = t + NT * kk;
        lds[SBASE + (idx >> 7) * ST + (idx & 127)] = 1.0f;
    }

    // this thread's fixed 16 elements: (row ob+j, col u) — phase-2 mapping
    float Ap0[16], Ap1[16];
    float SA0 = 0.f, SA1 = 0.f, SA1C = 0.f, D0 = 0.f, D1 = 0.f;
    #pragma unroll
    for (int j = 0; j < 16; ++j) {
        Ap0[j] = A0[(ob + j) * NN + u];
        Ap1[j] = A1[(ob + j) * NN + u];
        SA0 += Ap0[j]; SA1 += Ap1[j];
        SA1C += fmaxf(Ap1[j], 1e-20f);
    }
    float B = 0.f, r = 1.f, B18 = 0.f, B19 = 0.f;
    __syncthreads();

    #pragma unroll 1
    for (int k = 0; k < NH; ++k) {
        if (k == 18) B18 = B;        // bias of final phi0 (written this halfstep)
        if (k == 19) B19 = B;        // bias of final phi1

        // ---- phase 1: row conv of S -> D (transposed write, scaled by r) ----
        {
            const int rb0 = SBASE + u * ST + ob - RW;
            float acc[16];
            #pragma unroll
            for (int j = 0; j < 16; ++j) acc[j] = 0.f;
            #pragma unroll
            for (int i = 0; i < 48; ++i) {
                float v = lds[rb0 + i];
                const int p = i - 16;          // position relative to ob
                #pragma unroll
                for (int j = 0; j < 16; ++j) {
                    const int d = p - j;
                    if (d >= -RW && d <= RW)
                        acc[j] = fmaf(v, gt.g[d < 0 ? -d : d], acc[j]);
                }
            }
            const int wb = DBASE + ob * ST + u;
            #pragma unroll
            for (int j = 0; j < 16; ++j) lds[wb + j * ST] = acc[j] * r;
        }
        __syncthreads();

        // ---- phase 2: col conv D -> T, finalize S' = max(a,floor)/T ----
        float vmax = 0.f;
        {
            const int rb0 = DBASE + u * ST + ob - RW;
            float acc[16];
            #pragma unroll
            for (int j = 0; j < 16; ++j) acc[j] = 0.f;
            #pragma unroll
            for (int i = 0; i < 48; ++i) {
                float v = lds[rb0 + i];
                const int p = i - 16;
                #pragma unroll
                for (int j = 0; j < 16; ++j) {
                    const int d = p - j;
                    if (d >= -RW && d <= RW)
                        acc[j] = fmaf(v, gt.g[d < 0 ? -d : d], acc[j]);
                }
            }
            const int wb = SBASE + ob * ST + u;
            if (k == NH - 1) {
                // last halfstep: only the phi1*a1 dot is needed
                #pragma unroll
                for (int j = 0; j < 16; ++j) {
                    float amx = fmaxf(Ap1[j], 1e-20f);
                    float Un  = amx * __builtin_amdgcn_rcpf(acc[j]);
                    D1 = fmaf(Ap1[j], __logf(Un), D1);
                }
            } else if ((k & 1) == 0) {          // producing phi0 (uses a0)
                #pragma unroll
                for (int j = 0; j < 16; ++j) {
                    float amx = fmaxf(Ap0[j], 1e-20f);
                    float Un  = amx * __builtin_amdgcn_rcpf(acc[j]);
                    if (k == 18) D0 = fmaf(Ap0[j], __logf(Un), D0);
                    vmax = fmaxf(vmax, Un);
                    lds[wb + j * ST] = Un;
                }
            } else {                            // producing phi1 (uses a1)
                #pragma unroll
                for (int j = 0; j < 16; ++j) {
                    float amx = fmaxf(Ap1[j], 1e-20f);
                    float Un  = amx * __builtin_amdgcn_rcpf(acc[j]);
                    vmax = fmaxf(vmax, Un);
                    lds[wb + j * ST] = Un;
                }
            }
        }

        // ---- per-pair max reduce -> r, B update ----
        if (k < NH - 1) {
            #pragma unroll
            for (int off = 1; off < 64; off <<= 1)
                vmax = fmaxf(vmax, __shfl_xor(vmax, off, 64));
            if (lane == 0) red[wid] = vmax;
        }
        __syncthreads();                 // also orders phase-2 S writes
        if (k < NH - 1) {
            // all threads redundantly reduce red[0..15] (broadcast reads)
            const float4* r4 = (const float4*)red;
            float4 q0 = r4[0], q1 = r4[1], q2 = r4[2], q3 = r4[3];
            float m01 = fmaxf(fmaxf(q0.x, q0.y), fmaxf(q0.z, q0.w));
            float m23 = fmaxf(fmaxf(q1.x, q1.y), fmaxf(q1.z, q1.w));
            float m45 = fmaxf(fmaxf(q2.x, q2.y), fmaxf(q2.z, q2.w));
            float m67 = fmaxf(fmaxf(q3.x, q3.y), fmaxf(q3.z, q3.w));
            float mstar = fmaxf(fmaxf(m01, m23), fmaxf(m45, m67));
            B = -__logf(mstar) - B;
            r = __builtin_amdgcn_rcpf(mstar);
        }
    }

    // loss = eps*( sum phi0*a0 + sum phi1*a1 - sum p ),  sum p == SA1C exactly
    float part = D0 + D1 + B18 * SA0 + B19 * SA1 - SA1C;
    #pragma unroll
    for (int off = 1; off < 64; off <<= 1)
        part += __shfl_xor(part, off, 64);
    if (lane == 0) red[wid] = part;
    __syncthreads();
    if (t == 0) {
        float ssum = 0.f;
        #pragma unroll
        for (int w = 0; w < 16; ++w) ssum += red[w];
        out[pair] = 1e-3f * ssum;
    }
}

extern "C" void kernel_launch(void* const* d_in, const int* in_sizes, int n_in,
                              void* d_out, int out_size, void* d_ws, size_t ws_size,
                              hipStream_t stream) {
    const float* a0 = (const float*)d_in[0];   // (4,128,128) f32
    const float* a1 = (const float*)d_in[1];   // (4,128,128) f32
    float* out = (float*)d_out;                // (4,4) f32

    GTab gt;
    const float bb = 1e-3f / ((1.0f / 128.0f) * (1.0f / 128.0f));  // 16.384
    for (int d = 0; d <= RW; ++d)
        gt.g[d] = expf(-(float)(d * d) / bb);

    const size_t ldsBytes = (size_t)TOTD * sizeof(float);   // 152,768 B
    (void)hipFuncSetAttribute(reinterpret_cast<const void*>(sinkhorn_w2),
                              hipFuncAttributeMaxDynamicSharedMemorySize,
                              (int)ldsBytes);

    hipLaunchKernelGGL(sinkhorn_w2, dim3(16), dim3(NT), ldsBytes, stream,
                       a0, a1, out, gt);
}